// Round 1
// baseline (30315.414 us; speedup 1.0000x reference)
//
#include <hip/hip_runtime.h>

// ---- problem dims ----
#define B_ 64
#define T_ 100
#define D_ 32
#define L_ 64
#define K_ 16
#define H_ 50

// ---- output layout (flat float offsets, return order of reference tuple) ----
#define OUT_MU  0
#define OUT_SIG ((size_t)T_*B_*L_)                         // 409600
#define OUT_A   (OUT_SIG + (size_t)T_*B_*L_*L_)            // 26624000
#define OUT_C   (OUT_A + (size_t)B_*T_*L_*L_)              // 52838400

// ---- LDS strides (odd => <=2-way bank aliasing on b32) ----
#define SL   65   // 64-col matrices
#define SAUG 97   // forward augmented [S(32x32)|CS(32x64)]
#define SB2  129  // backward augmented [Sp1(64x64)|M(64x64)]

// ============================================================
// Generic per-thread 4x8-register-tile matmul on LDS operands.
// COL=false: C[i][j] = sum_k A[i*sa+k] * B[j*sb+k]      (A·B^T, rows dot rows)
// COL=true : C[i][j] = sum_k A[k*sa+i] * B[k*sb+j]      (A^T·B, cols dot cols)
// store: C = alpha*acc (+ C_old if ACC) (+ ident on diagonal)
// Threads with tid outside [0, numTiles) do nothing (enables pairing two
// independent matmuls on thread halves in one phase).
// ============================================================
template<int M, int N, int K, int TM, int TN, bool COL, bool ACC>
__device__ __forceinline__ void mm(const float* __restrict__ A, int sa,
                                   const float* __restrict__ B, int sb,
                                   float* __restrict__ C, int sc,
                                   float alpha, float ident, int tid)
{
    constexpr int NTC = N / TN;
    constexpr int NT  = (M / TM) * NTC;
    if ((unsigned)tid < (unsigned)NT) {
        const int tr = tid / NTC, tc = tid % NTC;
        const int i0 = tr * TM, j0 = tc * TN;
        float acc[TM][TN];
#pragma unroll
        for (int r = 0; r < TM; ++r)
#pragma unroll
            for (int c = 0; c < TN; ++c) acc[r][c] = 0.f;

#pragma unroll 4
        for (int k = 0; k < K; ++k) {
            float a[TM], b[TN];
#pragma unroll
            for (int r = 0; r < TM; ++r)
                a[r] = COL ? A[k * sa + i0 + r] : A[(i0 + r) * sa + k];
#pragma unroll
            for (int c = 0; c < TN; ++c)
                b[c] = COL ? B[k * sb + j0 + c] : B[(j0 + c) * sb + k];
#pragma unroll
            for (int r = 0; r < TM; ++r)
#pragma unroll
                for (int c = 0; c < TN; ++c) acc[r][c] += a[r] * b[c];
        }
#pragma unroll
        for (int r = 0; r < TM; ++r)
#pragma unroll
            for (int c = 0; c < TN; ++c) {
                float v = alpha * acc[r][c];
                if (ACC) v += C[(i0 + r) * sc + j0 + c];
                if (i0 + r == j0 + c) v += ident;
                C[(i0 + r) * sc + j0 + c] = v;
            }
    }
}

// ============================================================
// Kernel 1: MLP + softmax -> mixture weights w (B*T, K) into d_ws
// ============================================================
__global__ __launch_bounds__(256) void kv_mlp_kernel(
    const float* __restrict__ obs, const float* __restrict__ start_code,
    const float* __restrict__ W1, const float* __restrict__ b1,
    const float* __restrict__ W2, const float* __restrict__ b2,
    float* __restrict__ wout)
{
    int gid = blockIdx.x * blockDim.x + threadIdx.x;
    if (gid >= B_ * T_) return;
    int b = gid / T_, t = gid % T_;
    const float* src = (t == 0) ? start_code : (obs + ((size_t)b * T_ + (t - 1)) * D_);
    float joint[D_];
#pragma unroll
    for (int d = 0; d < D_; ++d) joint[d] = src[d];

    float h[H_];
    for (int j = 0; j < H_; ++j) {
        float s = b1[j];
#pragma unroll
        for (int d = 0; d < D_; ++d) s += joint[d] * W1[d * H_ + j];
        h[j] = fmaxf(s, 0.f);
    }
    float e[K_];
    float mx = -1e30f;
#pragma unroll
    for (int k = 0; k < K_; ++k) {
        float s = b2[k];
        for (int j = 0; j < H_; ++j) s += h[j] * W2[j * K_ + k];
        e[k] = s; mx = fmaxf(mx, s);
    }
    float ssum = 0.f;
#pragma unroll
    for (int k = 0; k < K_; ++k) { e[k] = expf(e[k] - mx); ssum += e[k]; }
    float inv = 1.f / ssum;
#pragma unroll
    for (int k = 0; k < K_; ++k) wout[(size_t)gid * K_ + k] = e[k] * inv;
}

// ============================================================
// Kernel 2: A_t = sum_k w_k A_k, C_t = sum_k w_k C_k  (one block per (b,t))
// ============================================================
__global__ __launch_bounds__(256) void kv_mix_kernel(
    const float* __restrict__ w, const float* __restrict__ A,
    const float* __restrict__ C, float* __restrict__ out)
{
    const int bid = blockIdx.x;            // = b*T + t
    const int tid = threadIdx.x;
    __shared__ float wsm[K_];
    if (tid < K_) wsm[tid] = w[(size_t)bid * K_ + tid];
    __syncthreads();
    float wk[K_];
#pragma unroll
    for (int k = 0; k < K_; ++k) wk[k] = wsm[k];

    float* outA = out + OUT_A + (size_t)bid * L_ * L_;
    for (int e = tid; e < L_ * L_; e += 256) {
        float s = 0.f;
#pragma unroll
        for (int k = 0; k < K_; ++k) s += wk[k] * A[k * L_ * L_ + e];
        outA[e] = s;
    }
    float* outC = out + OUT_C + (size_t)bid * D_ * L_;
    for (int e = tid; e < D_ * L_; e += 256) {
        float s = 0.f;
#pragma unroll
        for (int k = 0; k < K_; ++k) s += wk[k] * C[k * D_ * L_ + e];
        outC[e] = s;
    }
}

// ============================================================
// Kernel 3: forward Kalman filter, one block per batch element.
// Writes mu_f/Sig_f into the mu_smooth/Sig_smooth output slots.
// ============================================================
__global__ __launch_bounds__(256) void kv_forward_kernel(
    const float* __restrict__ obs, float* __restrict__ out)
{
    __shared__ float Sig[L_ * SL];   // predicted covariance (symmetric)
    __shared__ float Ct[D_ * SL];
    __shared__ float Aug[D_ * SAUG]; // [S | C*Sig] -> GJ -> [garbage | X=Kg^T]
    __shared__ float Im[L_ * SL];
    __shared__ float T1[L_ * SL];
    __shared__ float Sz[L_ * SL];
    __shared__ float At[L_ * SL];
    __shared__ float T2[L_ * SL];
    __shared__ float y[D_], r[D_], mu[L_], muz[L_];
    __shared__ float recips[L_];

    const int tid = threadIdx.x;
    const int b = blockIdx.x;

    for (int i = tid; i < L_; i += 256) mu[i] = 0.f;
    for (int e = tid; e < L_ * L_; e += 256) {
        int i = e >> 6, j = e & 63;
        Sig[i * SL + j] = (i == j) ? 20.f : 0.f;
    }
    __syncthreads();

    const float* obs_b = obs + (size_t)b * T_ * D_;
    const float* Cin = out + OUT_C + (size_t)b * T_ * D_ * L_;
    const float* Ain = out + OUT_A + (size_t)b * T_ * L_ * L_;

    for (int t = 0; t < T_; ++t) {
        // load C_t, y_t
        const float* cp = Cin + (size_t)t * D_ * L_;
        for (int e = tid; e < D_ * L_; e += 256) {
            int i = e >> 6, j = e & 63; Ct[i * SL + j] = cp[e];
        }
        if (tid < D_) y[tid] = obs_b[t * D_ + tid];
        __syncthreads();

        // CS = Ct * Sig (Sig symmetric: rows dot rows) -> Aug cols 32..95
        mm<D_, L_, L_, 4, 8, false, false>(Ct, SL, Sig, SL, Aug + D_, SAUG, 1.f, 0.f, tid);
        __syncthreads();

        // S = CS * Ct^T + 0.3 I -> Aug cols 0..31 ; r = y - Ct*mu (independent)
        mm<D_, D_, L_, 4, 8, false, false>(Aug + D_, SAUG, Ct, SL, Aug, SAUG, 1.f, 0.3f, tid);
        if (tid >= 192 && tid < 192 + D_) {
            int i = tid - 192; float s = 0.f;
            for (int l = 0; l < L_; ++l) s += Ct[i * SL + l] * mu[l];
            r[i] = y[i] - s;
        }
        __syncthreads();

        // Gauss-Jordan (no row normalization; SPD so no pivoting) on Aug 32x96
        for (int p = 0; p < D_; ++p) {
            if (tid == 0) recips[p] = 1.f / Aug[p * SAUG + p];
            __syncthreads();
            {
                int i = tid >> 3, jb = tid & 7;   // 8 threads/row, 12 cols each
                if (i != p) {
                    float f = Aug[i * SAUG + p] * recips[p];
                    for (int jj = jb; jj < 96; jj += 8)
                        if (jj != p) Aug[i * SAUG + jj] -= f * Aug[p * SAUG + jj];
                }
            }
            __syncthreads();
        }
        // normalize solution rows: X = D^-1 * transformed RHS
        for (int e = tid; e < D_ * L_; e += 256) {
            int i = e >> 6, j = e & 63;
            Aug[i * SAUG + D_ + j] *= recips[i];
        }
        __syncthreads();

        // mu_z = mu + Kg r  (Kg[l][i] = X[i][l])
        if (tid < L_) {
            float s = 0.f;
            for (int i = 0; i < D_; ++i) s += Aug[i * SAUG + D_ + tid] * r[i];
            muz[tid] = mu[tid] + s;
        }
        // Im = I - X^T * Ct  (cols dot cols, K=32)
        mm<L_, L_, D_, 4, 8, true, false>(Aug + D_, SAUG, Ct, SL, Im, SL, -1.f, 1.f, tid);
        __syncthreads();

        // T1 = Im * Sig (threads 0..127)  ||  Sz = 0.3 * X^T X (threads 128..255)
        mm<L_, L_, L_, 4, 8, false, false>(Im, SL, Sig, SL, T1, SL, 1.f, 0.f, tid);
        mm<L_, L_, D_, 4, 8, true, false>(Aug + D_, SAUG, Aug + D_, SAUG, Sz, SL, 0.3f, 0.f, tid - 128);
        __syncthreads();

        // Sz += T1 * Im^T   (Joseph form complete)
        mm<L_, L_, L_, 4, 8, false, true>(T1, SL, Im, SL, Sz, SL, 1.f, 0.f, tid);
        __syncthreads();

        // store filtered into smoothed slots; load A_t
        float* muo = out + OUT_MU + ((size_t)t * B_ + b) * L_;
        if (tid < L_) muo[tid] = muz[tid];
        float* so = out + OUT_SIG + ((size_t)t * B_ + b) * (size_t)(L_ * L_);
        for (int e = tid; e < L_ * L_; e += 256) {
            int i = e >> 6, j = e & 63; so[e] = Sz[i * SL + j];
        }
        const float* ap = Ain + (size_t)t * L_ * L_;
        for (int e = tid; e < L_ * L_; e += 256) {
            int i = e >> 6, j = e & 63; At[i * SL + j] = ap[e];
        }
        __syncthreads();

        // T2 = At * Sz (Sz symmetric)  ||  mu = At * muz (high threads)
        mm<L_, L_, L_, 4, 8, false, false>(At, SL, Sz, SL, T2, SL, 1.f, 0.f, tid);
        if (tid >= 192 && tid < 192 + L_) {
            int l = tid - 192; float s = 0.f;
            for (int m2 = 0; m2 < L_; ++m2) s += At[l * SL + m2] * muz[m2];
            mu[l] = s;
        }
        __syncthreads();

        // Sig = T2 * At^T + 0.8 I   (predicted covariance for t+1)
        mm<L_, L_, L_, 4, 8, false, false>(T2, SL, At, SL, Sig, SL, 1.f, 0.8f, tid);
        __syncthreads();
    }
}

// ============================================================
// Kernel 4: RTS smoother, one block per batch element, in-place on d_out.
// Recomputes Sp1 = A(t) Sf(t) A(t)^T + 0.8I (reference quirk: J uses A(t+1)).
// ============================================================
__global__ __launch_bounds__(256) void kv_backward_kernel(float* __restrict__ out)
{
    __shared__ float SsA[L_ * SL], SsB[L_ * SL];   // smoothed(t+1) / filtered(t) ping-pong
    __shared__ float AtA[L_ * SL], AtB[L_ * SL];   // A(t+1) / A(t) ping-pong
    __shared__ float Tt[L_ * SL];                  // temp: A(t)*Sf, later T3 = D1*X
    __shared__ float Aug[L_ * SB2];                // [Sp1 | A(t+1)*Sf] -> GJ -> [.|X=J^T]
    __shared__ float D1[L_ * SL];
    __shared__ float muA[L_], muB[L_], mf[L_], dmu[L_];
    __shared__ float recips[L_];

    const int tid = threadIdx.x;
    const int b = blockIdx.x;
    const float* Ain = out + OUT_A + (size_t)b * T_ * L_ * L_;

    float* Ss = SsA; float* Sf = SsB;
    float* At1 = AtA; float* Att = AtB;
    float* mus = muA; float* musN = muB;

    {   // init carry: smoothed(T-1) = filtered(T-1); A(t+1) = A[T-1]
        const float* sp = out + OUT_SIG + ((size_t)(T_ - 1) * B_ + b) * (size_t)(L_ * L_);
        for (int e = tid; e < L_ * L_; e += 256) {
            int i = e >> 6, j = e & 63; Ss[i * SL + j] = sp[e];
        }
        const float* mp = out + OUT_MU + ((size_t)(T_ - 1) * B_ + b) * L_;
        if (tid < L_) mus[tid] = mp[tid];
        const float* ap = Ain + (size_t)(T_ - 1) * L_ * L_;
        for (int e = tid; e < L_ * L_; e += 256) {
            int i = e >> 6, j = e & 63; At1[i * SL + j] = ap[e];
        }
    }
    __syncthreads();

    for (int t = T_ - 2; t >= 0; --t) {
        // load Sf(t), mf(t), A(t)
        const float* sp = out + OUT_SIG + ((size_t)t * B_ + b) * (size_t)(L_ * L_);
        for (int e = tid; e < L_ * L_; e += 256) {
            int i = e >> 6, j = e & 63; Sf[i * SL + j] = sp[e];
        }
        const float* mp = out + OUT_MU + ((size_t)t * B_ + b) * L_;
        if (tid < L_) mf[tid] = mp[tid];
        const float* ap = Ain + (size_t)t * L_ * L_;
        for (int e = tid; e < L_ * L_; e += 256) {
            int i = e >> 6, j = e & 63; Att[i * SL + j] = ap[e];
        }
        __syncthreads();

        // Tt = A(t) * Sf  (Sf symmetric)
        mm<L_, L_, L_, 4, 8, false, false>(Att, SL, Sf, SL, Tt, SL, 1.f, 0.f, tid);
        __syncthreads();

        // Sp1 = Tt*A(t)^T + 0.8I -> Aug[:,0:64]  ||  M = A(t+1)*Sf -> Aug[:,64:128]
        mm<L_, L_, L_, 4, 8, false, false>(Tt, SL, Att, SL, Aug, SB2, 1.f, 0.8f, tid);
        mm<L_, L_, L_, 4, 8, false, false>(At1, SL, Sf, SL, Aug + L_, SB2, 1.f, 0.f, tid - 128);
        __syncthreads();

        // D1 = Ss - Sp1 ; dmu = mus - A(t)*mf
        for (int e = tid; e < L_ * L_; e += 256) {
            int i = e >> 6, j = e & 63;
            D1[i * SL + j] = Ss[i * SL + j] - Aug[i * SB2 + j];
        }
        if (tid < L_) {
            float s = 0.f;
            for (int m2 = 0; m2 < L_; ++m2) s += Att[tid * SL + m2] * mf[m2];
            dmu[tid] = mus[tid] - s;
        }
        __syncthreads();

        // GJ on Aug 64x128: solve Sp1 * X = M  => X = J^T
        for (int p = 0; p < L_; ++p) {
            if (tid == 0) recips[p] = 1.f / Aug[p * SB2 + p];
            __syncthreads();
            {
                int i = tid >> 2, jb = tid & 3;   // 4 threads/row, 32 cols each
                if (i != p) {
                    float f = Aug[i * SB2 + p] * recips[p];
                    for (int jj = jb; jj < 128; jj += 4)
                        if (jj != p) Aug[i * SB2 + jj] -= f * Aug[p * SB2 + jj];
                }
            }
            __syncthreads();
        }
        for (int e = tid; e < L_ * L_; e += 256) {
            int i = e >> 6, j = e & 63;
            Aug[i * SB2 + L_ + j] *= recips[i];
        }
        __syncthreads();

        // mu_s = mf + J*dmu  (J[l][m] = X[m][l]) ; T3 = D1*X (D1 symmetric -> cols dot cols)
        if (tid < L_) {
            float s = 0.f;
            for (int m2 = 0; m2 < L_; ++m2) s += Aug[m2 * SB2 + L_ + tid] * dmu[m2];
            musN[tid] = mf[tid] + s;
        }
        mm<L_, L_, L_, 4, 8, true, false>(D1, SL, Aug + L_, SB2, Tt, SL, 1.f, 0.f, tid);
        __syncthreads();

        // Sig_s = Sf + X^T * T3   (in place into Sf)
        mm<L_, L_, L_, 4, 8, true, true>(Aug + L_, SB2, Tt, SL, Sf, SL, 1.f, 0.f, tid);
        __syncthreads();

        // store smoothed(t)
        float* so = out + OUT_SIG + ((size_t)t * B_ + b) * (size_t)(L_ * L_);
        for (int e = tid; e < L_ * L_; e += 256) {
            int i = e >> 6, j = e & 63; so[e] = Sf[i * SL + j];
        }
        float* muo = out + OUT_MU + ((size_t)t * B_ + b) * L_;
        if (tid < L_) muo[tid] = musN[tid];

        // rotate carries
        { float* tmp = Ss; Ss = Sf; Sf = tmp; }
        { float* tmp = At1; At1 = Att; Att = tmp; }
        { float* tmp = mus; mus = musN; musN = tmp; }
        __syncthreads();
    }
}

// ============================================================
extern "C" void kernel_launch(void* const* d_in, const int* in_sizes, int n_in,
                              void* d_out, int out_size, void* d_ws, size_t ws_size,
                              hipStream_t stream)
{
    const float* obs        = (const float*)d_in[0];
    const float* start_code = (const float*)d_in[1];
    const float* W1         = (const float*)d_in[2];
    const float* b1         = (const float*)d_in[3];
    const float* W2         = (const float*)d_in[4];
    const float* b2         = (const float*)d_in[5];
    const float* A          = (const float*)d_in[6];
    const float* C          = (const float*)d_in[7];
    float* out  = (float*)d_out;
    float* wbuf = (float*)d_ws;   // B*T*K floats = 400 KiB

    kv_mlp_kernel<<<(B_ * T_ + 255) / 256, 256, 0, stream>>>(obs, start_code, W1, b1, W2, b2, wbuf);
    kv_mix_kernel<<<B_ * T_, 256, 0, stream>>>(wbuf, A, C, out);
    kv_forward_kernel<<<B_, 256, 0, stream>>>(obs, out);
    kv_backward_kernel<<<B_, 256, 0, stream>>>(out);
}

// Round 6
// 7193.200 us; speedup vs baseline: 4.2145x; 4.2145x over previous
//
#include <hip/hip_runtime.h>

// ---- problem dims ----
#define B_ 64
#define T_ 100
#define D_ 32
#define L_ 64
#define K_ 16
#define H_ 50

// ---- output layout (flat float offsets, reference tuple return order) ----
#define OUT_MU  0
#define OUT_SIG ((size_t)T_*B_*L_)                         // 409600
#define OUT_A   (OUT_SIG + (size_t)T_*B_*L_*L_)            // 26624000
#define OUT_C   (OUT_A + (size_t)B_*T_*L_*L_)              // 52838400

// ---- LDS strides (odd => matmul reads are <=2-way bank aliased = free) ----
#define SL   65   // 64-col matrices
#define SAUG 97   // forward augmented [S(32x32)|CS(32x64)]
#define SB2  129  // backward augmented [Sp1(64x64)|M(64x64)]

// ============================================================
// Per-thread register-tile matmul on LDS operands.
// COL=false: C[i][j] = sum_k A[i*sa+k] * B[j*sb+k]   (A·B^T, rows dot rows)
// COL=true : C[i][j] = sum_k A[k*sa+i] * B[k*sb+j]   (A^T·B, cols dot cols)
// C = alpha*acc (+ C_old if ACC) (+ ident on diagonal).
// tid outside [0,NT) does nothing (enables half-block pairing).
// ============================================================
template<int M, int N, int K, int TM, int TN, bool COL, bool ACC>
__device__ __forceinline__ void mm(const float* __restrict__ A, int sa,
                                   const float* __restrict__ B, int sb,
                                   float* __restrict__ C, int sc,
                                   float alpha, float ident, int tid)
{
    constexpr int NTC = N / TN;
    constexpr int NT  = (M / TM) * NTC;
    if ((unsigned)tid < (unsigned)NT) {
        const int tr = tid / NTC, tc = tid % NTC;
        const int i0 = tr * TM, j0 = tc * TN;
        float acc[TM][TN];
#pragma unroll
        for (int r = 0; r < TM; ++r)
#pragma unroll
            for (int c = 0; c < TN; ++c) acc[r][c] = 0.f;

#pragma unroll 4
        for (int k = 0; k < K; ++k) {
            float a[TM], b[TN];
#pragma unroll
            for (int r = 0; r < TM; ++r)
                a[r] = COL ? A[k * sa + i0 + r] : A[(i0 + r) * sa + k];
#pragma unroll
            for (int c = 0; c < TN; ++c)
                b[c] = COL ? B[k * sb + j0 + c] : B[(j0 + c) * sb + k];
#pragma unroll
            for (int r = 0; r < TM; ++r)
#pragma unroll
                for (int c = 0; c < TN; ++c) acc[r][c] += a[r] * b[c];
        }
#pragma unroll
        for (int r = 0; r < TM; ++r)
#pragma unroll
            for (int c = 0; c < TN; ++c) {
                float v = alpha * acc[r][c];
                if (ACC) v += C[(i0 + r) * sc + j0 + c];
                if (i0 + r == j0 + c) v += ident;
                C[(i0 + r) * sc + j0 + c] = v;
            }
    }
}

// global (contiguous, 16B-aligned) -> LDS row-major [.. ][NCOLS] with stride
template<int NCOLS>
__device__ __forceinline__ void g2s4(float* __restrict__ dst, int stride,
                                     const float* __restrict__ src, int nchunks,
                                     int tid, int nth)
{
    for (int c = tid; c < nchunks; c += nth) {
        float4 v = reinterpret_cast<const float4*>(src)[c];
        int e = c << 2;
        int i = e / NCOLS, j = e % NCOLS;
        float* p = dst + i * stride + j;
        p[0] = v.x; p[1] = v.y; p[2] = v.z; p[3] = v.w;
    }
}
// LDS row-major with stride -> global contiguous
template<int NCOLS>
__device__ __forceinline__ void s2g4(float* __restrict__ dst,
                                     const float* __restrict__ src, int stride,
                                     int nchunks, int tid, int nth)
{
    for (int c = tid; c < nchunks; c += nth) {
        int e = c << 2;
        int i = e / NCOLS, j = e % NCOLS;
        const float* p = src + i * stride + j;
        reinterpret_cast<float4*>(dst)[c] = make_float4(p[0], p[1], p[2], p[3]);
    }
}

// ============================================================
// Kernel 1: MLP + softmax -> mixture weights w (B*T, K) into d_ws
// ============================================================
__global__ __launch_bounds__(256) void kv_mlp_kernel(
    const float* __restrict__ obs, const float* __restrict__ start_code,
    const float* __restrict__ W1, const float* __restrict__ b1,
    const float* __restrict__ W2, const float* __restrict__ b2,
    float* __restrict__ wout)
{
    int gid = blockIdx.x * blockDim.x + threadIdx.x;
    if (gid >= B_ * T_) return;
    int b = gid / T_, t = gid % T_;
    const float* src = (t == 0) ? start_code : (obs + ((size_t)b * T_ + (t - 1)) * D_);
    float joint[D_];
#pragma unroll
    for (int d = 0; d < D_; ++d) joint[d] = src[d];

    float h[H_];
    for (int j = 0; j < H_; ++j) {
        float s = b1[j];
#pragma unroll
        for (int d = 0; d < D_; ++d) s += joint[d] * W1[d * H_ + j];
        h[j] = fmaxf(s, 0.f);
    }
    float e[K_];
    float mx = -1e30f;
#pragma unroll
    for (int k = 0; k < K_; ++k) {
        float s = b2[k];
        for (int j = 0; j < H_; ++j) s += h[j] * W2[j * K_ + k];
        e[k] = s; mx = fmaxf(mx, s);
    }
    float ssum = 0.f;
#pragma unroll
    for (int k = 0; k < K_; ++k) { e[k] = expf(e[k] - mx); ssum += e[k]; }
    float inv = 1.f / ssum;
#pragma unroll
    for (int k = 0; k < K_; ++k) wout[(size_t)gid * K_ + k] = e[k] * inv;
}

// ============================================================
// Kernel 2: A_t = sum_k w_k A_k, C_t = sum_k w_k C_k (one block per (b,t))
// ============================================================
__global__ __launch_bounds__(256) void kv_mix_kernel(
    const float* __restrict__ w, const float* __restrict__ A,
    const float* __restrict__ C, float* __restrict__ out)
{
    const int bid = blockIdx.x;            // = b*T + t
    const int tid = threadIdx.x;
    __shared__ float wsm[K_];
    if (tid < K_) wsm[tid] = w[(size_t)bid * K_ + tid];
    __syncthreads();
    float wk[K_];
#pragma unroll
    for (int k = 0; k < K_; ++k) wk[k] = wsm[k];

    float* outA = out + OUT_A + (size_t)bid * L_ * L_;
    for (int e = tid; e < L_ * L_; e += 256) {
        float s = 0.f;
#pragma unroll
        for (int k = 0; k < K_; ++k) s += wk[k] * A[k * L_ * L_ + e];
        outA[e] = s;
    }
    float* outC = out + OUT_C + (size_t)bid * D_ * L_;
    for (int e = tid; e < D_ * L_; e += 256) {
        float s = 0.f;
#pragma unroll
        for (int k = 0; k < K_; ++k) s += wk[k] * C[k * D_ * L_ + e];
        outC[e] = s;
    }
}

// ============================================================
// Kernel 3: forward Kalman filter, one block (512 thr) per batch element.
// Math identical to R0 version (same k-order, same GJ arithmetic); phases
// paired on thread halves, one barrier per GJ pivot, skewed GJ columns.
// ============================================================
__global__ __launch_bounds__(512) void kv_forward_kernel(
    const float* __restrict__ obs, float* __restrict__ out)
{
    __shared__ float Sig[L_ * SL];
    __shared__ float Ct[D_ * SL];
    __shared__ float Aug[D_ * SAUG]; // [S | C*Sig] -> GJ -> [junk | X=Kg^T]
    __shared__ float Im[L_ * SL];
    __shared__ float T1[L_ * SL];
    __shared__ float Sz[L_ * SL];
    __shared__ float At[L_ * SL];
    __shared__ float T2[L_ * SL];
    __shared__ float y[D_], r[D_], mu[L_], muz[L_];
    __shared__ float recips[D_];

    const int tid = threadIdx.x;
    const int b = blockIdx.x;

    const float* obs_b = obs + (size_t)b * T_ * D_;
    const float* Cin = out + OUT_C + (size_t)b * T_ * D_ * L_;
    const float* Ain = out + OUT_A + (size_t)b * T_ * L_ * L_;

    // init: mu=0, Sig=20I, load Ct(0), y(0)
    for (int i = tid; i < L_; i += 512) mu[i] = 0.f;
    for (int e = tid; e < L_ * L_; e += 512) {
        int i = e >> 6, j = e & 63;
        Sig[i * SL + j] = (i == j) ? 20.f : 0.f;
    }
    g2s4<64>(Ct, SL, Cin, 512, tid, 512);
    if (tid < D_) y[tid] = obs_b[tid];
    __syncthreads();

    for (int t = 0; t < T_; ++t) {
        // P1: CS = Ct*Sig (Sig sym) -> Aug cols 32..95   || r = y - Ct*mu
        mm<D_, L_, L_, 2, 4, false, false>(Ct, SL, Sig, SL, Aug + D_, SAUG, 1.f, 0.f, tid);
        if (tid >= 480) {
            int i = tid - 480; float s = 0.f;
            for (int l = 0; l < L_; ++l) s += Ct[i * SL + l] * mu[l];
            r[i] = y[i] - s;
        }
        __syncthreads();

        // P2: S = CS*Ct^T + 0.3I -> Aug cols 0..31
        mm<D_, D_, L_, 2, 4, false, false>(Aug + D_, SAUG, Ct, SL, Aug, SAUG, 1.f, 0.3f, tid);
        __syncthreads();

        // P3: Gauss-Jordan 32x96 (SPD, no pivoting), 1 barrier/pivot, skewed cols
        for (int p = 0; p < D_; ++p) {
            float rcp = 1.f / Aug[p * SAUG + p];
            if (tid == 0) recips[p] = rcp;
            int i = tid >> 4, jb = tid & 15;         // 32 rows x 16 thr
            if (i != p) {
                float f = Aug[i * SAUG + p] * rcp;
                int c0 = i % 6;
                for (int s = 0; s < 6; ++s) {
                    int c = c0 + s; if (c >= 6) c -= 6;
                    int jj = jb + 16 * c;
                    if (jj != p) Aug[i * SAUG + jj] -= f * Aug[p * SAUG + jj];
                }
            }
            __syncthreads();
        }
        // P4: normalize solution rows: X = D^-1 * RHS
        for (int e = tid; e < D_ * L_; e += 512) {
            int i = e >> 6, j = e & 63;
            Aug[i * SAUG + D_ + j] *= recips[i];
        }
        __syncthreads();

        // P5: Im = I - X^T*Ct   || Sz = 0.3*X^T*X
        mm<L_, L_, D_, 4, 4, true, false>(Aug + D_, SAUG, Ct, SL, Im, SL, -1.f, 1.f, tid);
        mm<L_, L_, D_, 4, 4, true, false>(Aug + D_, SAUG, Aug + D_, SAUG, Sz, SL, 0.3f, 0.f, tid - 256);
        __syncthreads();

        // P6: T1 = Im*Sig   || load At || muz = mu + Kg r
        mm<L_, L_, L_, 4, 4, false, false>(Im, SL, Sig, SL, T1, SL, 1.f, 0.f, tid);
        if (tid >= 256 && tid < 448)
            g2s4<64>(At, SL, Ain + (size_t)t * L_ * L_, 1024, tid - 256, 192);
        if (tid >= 448) {
            int l = tid - 448; float s = 0.f;
            for (int i = 0; i < D_; ++i) s += Aug[i * SAUG + D_ + l] * r[i];
            muz[l] = mu[l] + s;
        }
        __syncthreads();

        // P7: Sz += T1*Im^T (Joseph complete)  || mu = At*muz ; store muz
        mm<L_, L_, L_, 4, 4, false, true>(T1, SL, Im, SL, Sz, SL, 1.f, 0.f, tid);
        if (tid >= 448) {
            int l = tid - 448; float s = 0.f;
            for (int m2 = 0; m2 < L_; ++m2) s += At[l * SL + m2] * muz[m2];
            mu[l] = s;
            out[OUT_MU + ((size_t)t * B_ + b) * L_ + l] = muz[l];
        }
        __syncthreads();

        // P8: T2 = At*Sz (Sz sym)   || store Sz -> SIG slot
        mm<L_, L_, L_, 4, 4, false, false>(At, SL, Sz, SL, T2, SL, 1.f, 0.f, tid);
        if (tid >= 256)
            s2g4<64>(out + OUT_SIG + ((size_t)t * B_ + b) * (size_t)(L_ * L_), Sz, SL, 1024, tid - 256, 256);
        __syncthreads();

        // P9: Sig = T2*At^T + 0.8I  || prefetch Ct(t+1), y(t+1)
        mm<L_, L_, L_, 4, 4, false, false>(T2, SL, At, SL, Sig, SL, 1.f, 0.8f, tid);
        if (tid >= 256 && t + 1 < T_) {
            if (tid < 480) g2s4<64>(Ct, SL, Cin + (size_t)(t + 1) * D_ * L_, 512, tid - 256, 224);
            else y[tid - 480] = obs_b[(t + 1) * D_ + (tid - 480)];
        }
        __syncthreads();
    }
}

// ============================================================
// Kernel 4a: parallel smoother-gain precompute, one block per (b,t), t<T-1.
//   Sp1 = A(t) Sf A(t)^T + 0.8I ; M = A(t+1) Sf ; solve Sp1 X = M (X = J^T)
//   U = Sf - X^T M  (-> SIG slot, in place) ; v = mf - J*(A(t) mf) (-> MU slot)
//   X -> ws
// ============================================================
__global__ __launch_bounds__(512) void kv_bwd_par_kernel(
    float* __restrict__ out, float* __restrict__ Xws)
{
    __shared__ float Sf[L_ * SL];
    __shared__ float Aa[L_ * SL];
    __shared__ float Ab[L_ * SL];
    __shared__ float Mb[L_ * SL];   // Tt = A(t)*Sf
    __shared__ float Mc[L_ * SL];   // M = A(t+1)*Sf (kept across GJ)
    __shared__ float Aug[L_ * SB2]; // [Sp1 | M] -> GJ -> [junk | X]
    __shared__ float mf[L_], mp1[L_], recips[L_];

    const int tid = threadIdx.x;
    const int bid = blockIdx.x;
    const int b = bid / (T_ - 1), t = bid % (T_ - 1);

    // L: load Sf(t), A(t), A(t+1), mf(t)
    g2s4<64>(Sf, SL, out + OUT_SIG + ((size_t)t * B_ + b) * (size_t)(L_ * L_), 1024, tid, 512);
    g2s4<64>(Aa, SL, out + OUT_A + ((size_t)b * T_ + t) * (size_t)(L_ * L_), 1024, tid, 512);
    g2s4<64>(Ab, SL, out + OUT_A + ((size_t)b * T_ + t + 1) * (size_t)(L_ * L_), 1024, tid, 512);
    if (tid < L_) mf[tid] = out[OUT_MU + ((size_t)t * B_ + b) * L_ + tid];
    __syncthreads();

    // P1: Mb = A(t)*Sf  || Mc = A(t+1)*Sf     (Sf symmetric)
    mm<L_, L_, L_, 4, 4, false, false>(Aa, SL, Sf, SL, Mb, SL, 1.f, 0.f, tid);
    mm<L_, L_, L_, 4, 4, false, false>(Ab, SL, Sf, SL, Mc, SL, 1.f, 0.f, tid - 256);
    __syncthreads();

    // P2: Aug_L = Mb*A(t)^T + 0.8I (Sp1)  || copy Mc -> Aug_R || mp1 = A(t)*mf
    mm<L_, L_, L_, 4, 4, false, false>(Mb, SL, Aa, SL, Aug, SB2, 1.f, 0.8f, tid);
    if (tid >= 256 && tid < 448) {
        for (int e = tid - 256; e < L_ * L_; e += 192) {
            int i = e >> 6, j = e & 63;
            Aug[i * SB2 + L_ + j] = Mc[i * SL + j];
        }
    }
    if (tid >= 448) {
        int l = tid - 448; float s = 0.f;
        for (int m2 = 0; m2 < L_; ++m2) s += Aa[l * SL + m2] * mf[m2];
        mp1[l] = s;
    }
    __syncthreads();

    // P3: GJ 64x128, 1 barrier/pivot, skewed columns (bank = 9i+jb, ~2-way)
    for (int p = 0; p < L_; ++p) {
        float rcp = 1.f / Aug[p * SB2 + p];
        if (tid == 0) recips[p] = rcp;
        int i = tid >> 3, jb = tid & 7;           // 64 rows x 8 thr
        if (i != p) {
            float f = Aug[i * SB2 + p] * rcp;
            for (int s = 0; s < 16; ++s) {
                int jj = jb + 8 * ((s + i) & 15);
                if (jj != p) Aug[i * SB2 + jj] -= f * Aug[p * SB2 + jj];
            }
        }
        __syncthreads();
    }
    // P4: normalize X rows
    for (int e = tid; e < L_ * L_; e += 512) {
        int i = e >> 6, j = e & 63;
        Aug[i * SB2 + L_ + j] *= recips[i];
    }
    __syncthreads();

    // P5: U = Sf - X^T*Mc (in place)  || store X->ws || v -> MU slot
    mm<L_, L_, L_, 4, 4, true, true>(Aug + L_, SB2, Mc, SL, Sf, SL, -1.f, 0.f, tid);
    if (tid >= 256 && tid < 448) {
        float* xd = Xws + ((size_t)b * (T_ - 1) + t) * (size_t)(L_ * L_);
        for (int c = tid - 256; c < 1024; c += 192) {
            int e = c << 2, i = e >> 6, j = e & 63;
            const float* p4 = Aug + i * SB2 + L_ + j;
            reinterpret_cast<float4*>(xd)[c] = make_float4(p4[0], p4[1], p4[2], p4[3]);
        }
    }
    if (tid >= 448) {
        int l = tid - 448; float s = 0.f;
        for (int m2 = 0; m2 < L_; ++m2) s += Aug[m2 * SB2 + L_ + l] * mp1[m2];
        out[OUT_MU + ((size_t)t * B_ + b) * L_ + l] = mf[l] - s;
    }
    __syncthreads();

    // P6: store U -> SIG slot
    s2g4<64>(out + OUT_SIG + ((size_t)t * B_ + b) * (size_t)(L_ * L_), Sf, SL, 1024, tid, 512);
}

// ============================================================
// Kernel 4b: sequential smoother recursion, one block (512 thr) per chain.
//   Sig_s(t) = U(t) + X^T Sig_s(t+1) X ; mu_s(t) = v(t) + X^T-dot mu_s(t+1)
// Double-buffered prefetch of X(t-1), U(t-1), v(t-1) under compute.
// ============================================================
__global__ __launch_bounds__(512) void kv_smooth_seq_kernel(
    float* __restrict__ out, const float* __restrict__ Xws)
{
    __shared__ float SbufA[L_ * SL], SbufB[L_ * SL], Pb[L_ * SL];
    __shared__ float XbA[L_ * SL], XbB[L_ * SL];
    __shared__ float musA[L_], musB[L_], vA[L_], vB[L_];

    const int tid = threadIdx.x;
    const int b = blockIdx.x;

    float *Sa = SbufA, *Sb = SbufB, *Xc = XbA, *Xn = XbB;
    float *mus = musA, *musN = musB, *vc = vA, *vn = vB;

    // preload: Sa=Sig_s(T-1)=Sf(T-1); Sb=U(T-2); Xc=X(T-2); mus=mu(T-1); vc=v(T-2)
    g2s4<64>(Sa, SL, out + OUT_SIG + ((size_t)(T_ - 1) * B_ + b) * (size_t)(L_ * L_), 1024, tid, 512);
    g2s4<64>(Sb, SL, out + OUT_SIG + ((size_t)(T_ - 2) * B_ + b) * (size_t)(L_ * L_), 1024, tid, 512);
    g2s4<64>(Xc, SL, Xws + ((size_t)b * (T_ - 1) + (T_ - 2)) * (size_t)(L_ * L_), 1024, tid, 512);
    if (tid < L_) mus[tid] = out[OUT_MU + ((size_t)(T_ - 1) * B_ + b) * L_ + tid];
    else if (tid < 2 * L_) vc[tid - L_] = out[OUT_MU + ((size_t)(T_ - 2) * B_ + b) * L_ + (tid - L_)];
    __syncthreads();

    for (int t = T_ - 2; t >= 0; --t) {
        // P1: Pb = Sig_s(t+1)*Xc (Sa sym -> coldot) || prefetch X(t-1) || musN
        mm<L_, L_, L_, 4, 4, true, false>(Sa, SL, Xc, SL, Pb, SL, 1.f, 0.f, tid);
        if (tid >= 256 && tid < 448 && t > 0)
            g2s4<64>(Xn, SL, Xws + ((size_t)b * (T_ - 1) + (t - 1)) * (size_t)(L_ * L_), 1024, tid - 256, 192);
        if (tid >= 448) {
            int l = tid - 448; float s = 0.f;
            for (int m2 = 0; m2 < L_; ++m2) s += Xc[m2 * SL + l] * mus[m2];
            musN[l] = vc[l] + s;
        }
        __syncthreads();

        // P2: Sb += Xc^T*Pb (Sb holds U(t)) || prefetch U(t-1)->Sa, v(t-1)
        mm<L_, L_, L_, 4, 4, true, true>(Xc, SL, Pb, SL, Sb, SL, 1.f, 0.f, tid);
        if (t > 0) {
            if (tid >= 256 && tid < 480)
                g2s4<64>(Sa, SL, out + OUT_SIG + ((size_t)(t - 1) * B_ + b) * (size_t)(L_ * L_), 1024, tid - 256, 224);
            if (tid >= 480) {
                for (int l = tid - 480; l < L_; l += 32)
                    vn[l] = out[OUT_MU + ((size_t)(t - 1) * B_ + b) * L_ + l];
            }
        }
        __syncthreads();

        // P3: store Sig_s(t), mu_s(t)
        s2g4<64>(out + OUT_SIG + ((size_t)t * B_ + b) * (size_t)(L_ * L_), Sb, SL, 1024, tid, 512);
        if (tid < L_) out[OUT_MU + ((size_t)t * B_ + b) * L_ + tid] = musN[tid];
        __syncthreads();

        // rotate: new carry = Sb; new U-target = old Sa (prefetched)
        { float* tmp = Sa; Sa = Sb; Sb = tmp; }
        { float* tmp = Xc; Xc = Xn; Xn = tmp; }
        { float* tmp = mus; mus = musN; musN = tmp; }
        { float* tmp = vc; vc = vn; vn = tmp; }
    }
}

// ============================================================
// Fallback: R0 monolithic backward (used only if ws_size too small for X)
// ============================================================
__global__ __launch_bounds__(256) void kv_backward_fallback(float* __restrict__ out)
{
    __shared__ float SsA[L_ * SL], SsB[L_ * SL];
    __shared__ float AtA[L_ * SL], AtB[L_ * SL];
    __shared__ float Tt[L_ * SL];
    __shared__ float Aug[L_ * SB2];
    __shared__ float D1[L_ * SL];
    __shared__ float muA[L_], muB[L_], mf[L_], dmu[L_];
    __shared__ float recips[L_];

    const int tid = threadIdx.x;
    const int b = blockIdx.x;
    const float* Ain = out + OUT_A + (size_t)b * T_ * L_ * L_;

    float* Ss = SsA; float* Sf = SsB;
    float* At1 = AtA; float* Att = AtB;
    float* mus = muA; float* musN = muB;

    {
        const float* sp = out + OUT_SIG + ((size_t)(T_ - 1) * B_ + b) * (size_t)(L_ * L_);
        for (int e = tid; e < L_ * L_; e += 256) {
            int i = e >> 6, j = e & 63; Ss[i * SL + j] = sp[e];
        }
        const float* mp = out + OUT_MU + ((size_t)(T_ - 1) * B_ + b) * L_;
        if (tid < L_) mus[tid] = mp[tid];
        const float* ap = Ain + (size_t)(T_ - 1) * L_ * L_;
        for (int e = tid; e < L_ * L_; e += 256) {
            int i = e >> 6, j = e & 63; At1[i * SL + j] = ap[e];
        }
    }
    __syncthreads();

    for (int t = T_ - 2; t >= 0; --t) {
        const float* sp = out + OUT_SIG + ((size_t)t * B_ + b) * (size_t)(L_ * L_);
        for (int e = tid; e < L_ * L_; e += 256) {
            int i = e >> 6, j = e & 63; Sf[i * SL + j] = sp[e];
        }
        const float* mp = out + OUT_MU + ((size_t)t * B_ + b) * L_;
        if (tid < L_) mf[tid] = mp[tid];
        const float* ap = Ain + (size_t)t * L_ * L_;
        for (int e = tid; e < L_ * L_; e += 256) {
            int i = e >> 6, j = e & 63; Att[i * SL + j] = ap[e];
        }
        __syncthreads();

        mm<L_, L_, L_, 4, 8, false, false>(Att, SL, Sf, SL, Tt, SL, 1.f, 0.f, tid);
        __syncthreads();

        mm<L_, L_, L_, 4, 8, false, false>(Tt, SL, Att, SL, Aug, SB2, 1.f, 0.8f, tid);
        mm<L_, L_, L_, 4, 8, false, false>(At1, SL, Sf, SL, Aug + L_, SB2, 1.f, 0.f, tid - 128);
        __syncthreads();

        for (int e = tid; e < L_ * L_; e += 256) {
            int i = e >> 6, j = e & 63;
            D1[i * SL + j] = Ss[i * SL + j] - Aug[i * SB2 + j];
        }
        if (tid < L_) {
            float s = 0.f;
            for (int m2 = 0; m2 < L_; ++m2) s += Att[tid * SL + m2] * mf[m2];
            dmu[tid] = mus[tid] - s;
        }
        __syncthreads();

        for (int p = 0; p < L_; ++p) {
            if (tid == 0) recips[p] = 1.f / Aug[p * SB2 + p];
            __syncthreads();
            {
                int i = tid >> 2, jb = tid & 3;
                if (i != p) {
                    float f = Aug[i * SB2 + p] * recips[p];
                    for (int jj = jb; jj < 128; jj += 4)
                        if (jj != p) Aug[i * SB2 + jj] -= f * Aug[p * SB2 + jj];
                }
            }
            __syncthreads();
        }
        for (int e = tid; e < L_ * L_; e += 256) {
            int i = e >> 6, j = e & 63;
            Aug[i * SB2 + L_ + j] *= recips[i];
        }
        __syncthreads();

        if (tid < L_) {
            float s = 0.f;
            for (int m2 = 0; m2 < L_; ++m2) s += Aug[m2 * SB2 + L_ + tid] * dmu[m2];
            musN[tid] = mf[tid] + s;
        }
        mm<L_, L_, L_, 4, 8, true, false>(D1, SL, Aug + L_, SB2, Tt, SL, 1.f, 0.f, tid);
        __syncthreads();

        mm<L_, L_, L_, 4, 8, true, true>(Aug + L_, SB2, Tt, SL, Sf, SL, 1.f, 0.f, tid);
        __syncthreads();

        float* so = out + OUT_SIG + ((size_t)t * B_ + b) * (size_t)(L_ * L_);
        for (int e = tid; e < L_ * L_; e += 256) {
            int i = e >> 6, j = e & 63; so[e] = Sf[i * SL + j];
        }
        float* muo = out + OUT_MU + ((size_t)t * B_ + b) * L_;
        if (tid < L_) muo[tid] = musN[tid];

        { float* tmp = Ss; Ss = Sf; Sf = tmp; }
        { float* tmp = At1; At1 = Att; Att = tmp; }
        { float* tmp = mus; mus = musN; musN = tmp; }
        __syncthreads();
    }
}

// ============================================================
extern "C" void kernel_launch(void* const* d_in, const int* in_sizes, int n_in,
                              void* d_out, int out_size, void* d_ws, size_t ws_size,
                              hipStream_t stream)
{
    const float* obs        = (const float*)d_in[0];
    const float* start_code = (const float*)d_in[1];
    const float* W1         = (const float*)d_in[2];
    const float* b1         = (const float*)d_in[3];
    const float* W2         = (const float*)d_in[4];
    const float* b2         = (const float*)d_in[5];
    const float* A          = (const float*)d_in[6];
    const float* C          = (const float*)d_in[7];
    float* out  = (float*)d_out;
    float* wbuf = (float*)d_ws;   // B*T*K floats = 400 KiB at offset 0

    const size_t XOFF = (size_t)1 << 20;                                 // 1 MiB
    const size_t NEED = XOFF + (size_t)B_ * (T_ - 1) * L_ * L_ * sizeof(float);

    kv_mlp_kernel<<<(B_ * T_ + 255) / 256, 256, 0, stream>>>(obs, start_code, W1, b1, W2, b2, wbuf);
    kv_mix_kernel<<<B_ * T_, 256, 0, stream>>>(wbuf, A, C, out);
    kv_forward_kernel<<<B_, 512, 0, stream>>>(obs, out);

    if (ws_size >= NEED) {
        float* Xws = (float*)((char*)d_ws + XOFF);
        kv_bwd_par_kernel<<<B_ * (T_ - 1), 512, 0, stream>>>(out, Xws);
        kv_smooth_seq_kernel<<<B_, 512, 0, stream>>>(out, Xws);
    } else {
        kv_backward_fallback<<<64, 256, 0, stream>>>(out);
    }
}